// Round 1
// baseline (3359.036 us; speedup 1.0000x reference)
//
#include <hip/hip_runtime.h>
#include <math.h>

#define U_N 10000
#define G_N 3000
#define I_N 8000
#define D_N 32
#define NNZ_UI 720000
#define NNZ_GI 440000
#define L_MEM 20
#define B_N 4096
#define UI_N (U_N + I_N)   // 18000
#define GI_N (G_N + I_N)   // 11000
#define CAP 128            // max degree per row (Poisson(40); P(>128) ~ 1e-26)

static __host__ int cdiv(int a, int b) { return (a + b - 1) / b; }

// ---------------- utility kernels ----------------

__global__ __launch_bounds__(256) void copy_f(float* __restrict__ dst,
                                              const float* __restrict__ src, int n) {
    int i = blockIdx.x * 256 + threadIdx.x;
    if (i < n) dst[i] = src[i];
}

__global__ __launch_bounds__(256) void mean4(const float* __restrict__ a,
                                             const float* __restrict__ b,
                                             const float* __restrict__ c,
                                             const float* __restrict__ d,
                                             float* __restrict__ out, int n) {
    int i = blockIdx.x * 256 + threadIdx.x;
    if (i < n) out[i] = 0.25f * (a[i] + b[i] + c[i] + d[i]);
}

// ---------------- sparse: bucket build + gather SPMM ----------------

__global__ __launch_bounds__(256) void bucket_fill(const int* __restrict__ rows,
                                                   const int* __restrict__ cols,
                                                   const float* __restrict__ vals,
                                                   int nnz, int* __restrict__ cnt,
                                                   int* __restrict__ bcols,
                                                   float* __restrict__ bvals) {
    int i = blockIdx.x * 256 + threadIdx.x;
    if (i >= nnz) return;
    int r = rows[i];
    int pos = atomicAdd(&cnt[r], 1);
    if (pos < CAP) {
        bcols[(size_t)r * CAP + pos] = cols[i];
        bvals[(size_t)r * CAP + pos] = vals[i];
    }
}

// out[row, d] = sum_j bvals[row][j] * x[bcols[row][j], d]   (32-lane group per row)
__global__ __launch_bounds__(256) void spmm_bucket(const int* __restrict__ cnt,
                                                   const int* __restrict__ bcols,
                                                   const float* __restrict__ bvals,
                                                   const float* __restrict__ x,
                                                   float* __restrict__ out, int nrows) {
    int row = blockIdx.x * 8 + (threadIdx.x >> 5);
    if (row >= nrows) return;
    int d = threadIdx.x & 31;
    int deg = cnt[row];
    if (deg > CAP) deg = CAP;
    const int* bc = bcols + (size_t)row * CAP;
    const float* bv = bvals + (size_t)row * CAP;
    float acc = 0.f;
    int j = 0;
    for (; j + 1 < deg; j += 2) {
        int c0 = bc[j], c1 = bc[j + 1];
        float v0 = bv[j], v1 = bv[j + 1];
        acc += v0 * x[c0 * 32 + d];
        acc += v1 * x[c1 * 32 + d];
    }
    if (j < deg) acc += bv[j] * x[bc[j] * 32 + d];
    out[(size_t)row * 32 + d] = acc;
}

// ---------------- dense: out[N,32] = Ov[N,N] @ x[N,32];  acc += out ----------------
// block = 256 threads = 8 row-groups x 32 d-lanes; 4 rows per thread -> 32 rows/block

__global__ __launch_bounds__(256) void dense_nx32(const float* __restrict__ Ov,
                                                  const float* __restrict__ x,
                                                  float* __restrict__ xout,
                                                  float* __restrict__ acc, int N) {
    const int d = threadIdx.x & 31;
    const int r0 = blockIdx.x * 32 + (threadIdx.x >> 5) * 4;
    if (r0 >= N) return;  // N % 4 == 0, so all 4 rows valid when r0 < N
    float a0 = 0.f, a1 = 0.f, a2 = 0.f, a3 = 0.f;
    const float* p0 = Ov + (size_t)r0 * N;
    const float* p1 = p0 + N;
    const float* p2 = p1 + N;
    const float* p3 = p2 + N;
    const float* xp = x + d;
#pragma unroll 2
    for (int c = 0; c < N; c += 4) {
        float x0 = xp[(c + 0) * 32];
        float x1 = xp[(c + 1) * 32];
        float x2 = xp[(c + 2) * 32];
        float x3 = xp[(c + 3) * 32];
        float4 o0 = *(const float4*)(p0 + c);
        float4 o1 = *(const float4*)(p1 + c);
        float4 o2 = *(const float4*)(p2 + c);
        float4 o3 = *(const float4*)(p3 + c);
        a0 = fmaf(o0.x, x0, fmaf(o0.y, x1, fmaf(o0.z, x2, fmaf(o0.w, x3, a0))));
        a1 = fmaf(o1.x, x0, fmaf(o1.y, x1, fmaf(o1.z, x2, fmaf(o1.w, x3, a1))));
        a2 = fmaf(o2.x, x0, fmaf(o2.y, x1, fmaf(o2.z, x2, fmaf(o2.w, x3, a2))));
        a3 = fmaf(o3.x, x0, fmaf(o3.y, x1, fmaf(o3.z, x2, fmaf(o3.w, x3, a3))));
    }
    size_t o = (size_t)r0 * 32 + d;
    xout[o]      = a0; acc[o]      += a0;
    xout[o + 32] = a1; acc[o + 32] += a1;
    xout[o + 64] = a2; acc[o + 64] += a2;
    xout[o + 96] = a3; acc[o + 96] += a3;
}

// ---------------- pooling, gate, final mix, predict ----------------

__global__ __launch_bounds__(256) void pool_members(const int* __restrict__ users,
                                                    const float* __restrict__ mask,
                                                    const float* __restrict__ accu,
                                                    float* __restrict__ gul) {
    int gid = blockIdx.x * 256 + threadIdx.x;
    if (gid >= G_N * 32) return;
    int g = gid >> 5, d = gid & 31;
    float s = 0.f;
#pragma unroll
    for (int l = 0; l < L_MEM; ++l) {
        int u = users[g * L_MEM + l];
        s += mask[g * L_MEM + l] * accu[(size_t)u * 32 + d];
    }
    gul[gid] = s;
}

// 2G rows; 32 lanes per row. h = relu(x @ W1 + b1); w = sigmoid(h . w2 + b2)
__global__ __launch_bounds__(256) void gate_kernel(const float* __restrict__ gemb,
                                                   const float* __restrict__ gul,
                                                   const float* __restrict__ W1,
                                                   const float* __restrict__ b1,
                                                   const float* __restrict__ w2,
                                                   const float* __restrict__ b2,
                                                   float* __restrict__ wout) {
    int row = blockIdx.x * 8 + (threadIdx.x >> 5);
    int j = threadIdx.x & 31;
    if (row >= 2 * G_N) return;
    const float* xrow = (row < G_N) ? (gemb + (size_t)row * 32)
                                    : (gul + (size_t)(row - G_N) * 32);
    float xv = xrow[j];
    float h = b1[j];
#pragma unroll
    for (int k = 0; k < 32; ++k) {
        float xk = __shfl(xv, k, 32);
        h = fmaf(xk, W1[k * 32 + j], h);
    }
    h = fmaxf(h, 0.f);
    float t = h * w2[j];
#pragma unroll
    for (int off = 16; off >= 1; off >>= 1) t += __shfl_xor(t, off, 32);
    if (j == 0) wout[row] = 1.f / (1.f + expf(-(t + b2[0])));
}

__global__ __launch_bounds__(256) void final_mix(const float* __restrict__ wout,
                                                 const float* __restrict__ gemb,
                                                 const float* __restrict__ gul,
                                                 float* __restrict__ gfin) {
    int i = blockIdx.x * 256 + threadIdx.x;
    if (i >= G_N * 32) return;
    int g = i >> 5;
    gfin[i] = wout[g] * gemb[i] + wout[G_N + g] * gul[i];
}

__global__ __launch_bounds__(256) void predict_kernel(const int* __restrict__ gidx,
                                                      const int* __restrict__ iidx,
                                                      const float* __restrict__ gfin,
                                                      const float* __restrict__ iacc,
                                                      const float* __restrict__ pw1,
                                                      const float* __restrict__ pb1,
                                                      const float* __restrict__ pw2,
                                                      const float* __restrict__ pb2,
                                                      float* __restrict__ out) {
    int b = blockIdx.x * 256 + threadIdx.x;
    if (b >= B_N) return;
    const float* ge = gfin + (size_t)gidx[b] * 32;
    const float* ie = iacc + (size_t)iidx[b] * 32;
    float p[8];
#pragma unroll
    for (int j = 0; j < 8; ++j) p[j] = pb1[j];
    for (int d = 0; d < 32; ++d) {
        float t = ge[d] * ie[d];
#pragma unroll
        for (int j = 0; j < 8; ++j) p[j] = fmaf(t, pw1[d * 8 + j], p[j]);
    }
    float s = pb2[0];
#pragma unroll
    for (int j = 0; j < 8; ++j) s = fmaf(fmaxf(p[j], 0.f), pw2[j], s);
    out[b] = 1.f / (1.f + expf(-s));
}

// ---------------- launcher ----------------

extern "C" void kernel_launch(void* const* d_in, const int* in_sizes, int n_in,
                              void* d_out, int out_size, void* d_ws, size_t ws_size,
                              hipStream_t stream) {
    const int*   gin   = (const int*)d_in[0];
    const int*   iin   = (const int*)d_in[1];
    const float* uemb  = (const float*)d_in[2];
    const float* gemb0 = (const float*)d_in[3];
    const float* iemb0 = (const float*)d_in[4];
    const int*   uir   = (const int*)d_in[5];
    const int*   uic   = (const int*)d_in[6];
    const float* uiv   = (const float*)d_in[7];
    const int*   gir   = (const int*)d_in[8];
    const int*   gic   = (const int*)d_in[9];
    const float* giv   = (const float*)d_in[10];
    const float* ov_u  = (const float*)d_in[11];
    const float* ov_i  = (const float*)d_in[12];
    const int*   agu   = (const int*)d_in[13];
    const float* agm   = (const float*)d_in[14];
    const float* gw1   = (const float*)d_in[15];
    const float* gb1   = (const float*)d_in[16];
    const float* gw2   = (const float*)d_in[17];
    const float* gb2   = (const float*)d_in[18];
    const float* pw1   = (const float*)d_in[19];
    const float* pb1   = (const float*)d_in[20];
    const float* pw2   = (const float*)d_in[21];
    const float* pb2   = (const float*)d_in[22];
    float* out = (float*)d_out;

    // bump allocator over d_ws
    char* wp = (char*)d_ws;
    auto alloc = [&](size_t nbytes) -> void* {
        void* p = (void*)wp;
        wp += (nbytes + 255) & ~(size_t)255;
        return p;
    };
    int*   cnt_ui   = (int*)alloc((size_t)UI_N * 4);
    int*   bcols_ui = (int*)alloc((size_t)UI_N * CAP * 4);
    float* bvals_ui = (float*)alloc((size_t)UI_N * CAP * 4);
    int*   cnt_gi   = (int*)alloc((size_t)GI_N * 4);
    int*   bcols_gi = (int*)alloc((size_t)GI_N * CAP * 4);
    float* bvals_gi = (float*)alloc((size_t)GI_N * CAP * 4);

    float* ui0  = (float*)alloc((size_t)UI_N * 32 * 4);
    float* ui1  = (float*)alloc((size_t)UI_N * 32 * 4);
    float* ui2  = (float*)alloc((size_t)UI_N * 32 * 4);
    float* ui3  = (float*)alloc((size_t)UI_N * 32 * 4);
    float* gi0  = (float*)alloc((size_t)GI_N * 32 * 4);
    float* gi1  = (float*)alloc((size_t)GI_N * 32 * 4);
    float* gi2  = (float*)alloc((size_t)GI_N * 32 * 4);
    float* gi3  = (float*)alloc((size_t)GI_N * 32 * 4);
    float* uefu = (float*)alloc((size_t)U_N * 32 * 4);
    float* iefu = (float*)alloc((size_t)I_N * 32 * 4);
    float* iemb = (float*)alloc((size_t)I_N * 32 * 4);
    float* tmp  = (float*)alloc((size_t)GI_N * 32 * 4);
    float* gt1  = (float*)alloc((size_t)G_N * 32 * 4);
    float* gt3  = (float*)alloc((size_t)G_N * 32 * 4);
    float* gemb = (float*)alloc((size_t)G_N * 32 * 4);
    float* accu = (float*)alloc((size_t)U_N * 32 * 4);
    float* uea  = (float*)alloc((size_t)U_N * 32 * 4);
    float* ueb  = (float*)alloc((size_t)U_N * 32 * 4);
    float* gul  = (float*)alloc((size_t)G_N * 32 * 4);
    float* wg   = (float*)alloc((size_t)2 * G_N * 4);
    float* gfin = (float*)alloc((size_t)G_N * 32 * 4);
    float* iacc = (float*)alloc((size_t)I_N * 32 * 4);
    float* ita  = (float*)alloc((size_t)I_N * 32 * 4);
    float* itb  = (float*)alloc((size_t)I_N * 32 * 4);

    // --- build per-row buckets for both graphs ---
    hipMemsetAsync(cnt_ui, 0, (size_t)UI_N * 4, stream);
    hipMemsetAsync(cnt_gi, 0, (size_t)GI_N * 4, stream);
    bucket_fill<<<cdiv(NNZ_UI, 256), 256, 0, stream>>>(uir, uic, uiv, NNZ_UI,
                                                       cnt_ui, bcols_ui, bvals_ui);
    bucket_fill<<<cdiv(NNZ_GI, 256), 256, 0, stream>>>(gir, gic, giv, NNZ_GI,
                                                       cnt_gi, bcols_gi, bvals_gi);

    // --- user-item propagation (3 layers) ---
    copy_f<<<cdiv(U_N * 32, 256), 256, 0, stream>>>(ui0, uemb, U_N * 32);
    copy_f<<<cdiv(I_N * 32, 256), 256, 0, stream>>>(ui0 + (size_t)U_N * 32, iemb0, I_N * 32);
    spmm_bucket<<<cdiv(UI_N, 8), 256, 0, stream>>>(cnt_ui, bcols_ui, bvals_ui, ui0, ui1, UI_N);
    spmm_bucket<<<cdiv(UI_N, 8), 256, 0, stream>>>(cnt_ui, bcols_ui, bvals_ui, ui1, ui2, UI_N);
    spmm_bucket<<<cdiv(UI_N, 8), 256, 0, stream>>>(cnt_ui, bcols_ui, bvals_ui, ui2, ui3, UI_N);
    mean4<<<cdiv(U_N * 32, 256), 256, 0, stream>>>(ui0, ui1, ui2, ui3, uefu, U_N * 32);
    mean4<<<cdiv(I_N * 32, 256), 256, 0, stream>>>(ui0 + (size_t)U_N * 32, ui1 + (size_t)U_N * 32,
                                                   ui2 + (size_t)U_N * 32, ui3 + (size_t)U_N * 32,
                                                   iefu, I_N * 32);

    // --- group-item propagation (3 layers) ---
    copy_f<<<cdiv(G_N * 32, 256), 256, 0, stream>>>(gi0, gemb0, G_N * 32);
    copy_f<<<cdiv(I_N * 32, 256), 256, 0, stream>>>(gi0 + (size_t)G_N * 32, iefu, I_N * 32);
    spmm_bucket<<<cdiv(GI_N, 8), 256, 0, stream>>>(cnt_gi, bcols_gi, bvals_gi, gi0, gi1, GI_N);
    spmm_bucket<<<cdiv(GI_N, 8), 256, 0, stream>>>(cnt_gi, bcols_gi, bvals_gi, gi1, gi2, GI_N);
    spmm_bucket<<<cdiv(GI_N, 8), 256, 0, stream>>>(cnt_gi, bcols_gi, bvals_gi, gi2, gi3, GI_N);
    mean4<<<cdiv(I_N * 32, 256), 256, 0, stream>>>(gi0 + (size_t)G_N * 32, gi1 + (size_t)G_N * 32,
                                                   gi2 + (size_t)G_N * 32, gi3 + (size_t)G_N * 32,
                                                   iemb, I_N * 32);

    // --- g_layers odd terms: spmm over concat([group_emb, item_layers[i-1]]), rows < G only ---
    copy_f<<<cdiv(G_N * 32, 256), 256, 0, stream>>>(tmp, gemb0, G_N * 32);
    copy_f<<<cdiv(I_N * 32, 256), 256, 0, stream>>>(tmp + (size_t)G_N * 32, iemb0, I_N * 32);
    spmm_bucket<<<cdiv(G_N, 8), 256, 0, stream>>>(cnt_gi, bcols_gi, bvals_gi, tmp, gt1, G_N);
    copy_f<<<cdiv(I_N * 32, 256), 256, 0, stream>>>(tmp + (size_t)G_N * 32,
                                                    ui2 + (size_t)U_N * 32, I_N * 32);
    spmm_bucket<<<cdiv(G_N, 8), 256, 0, stream>>>(cnt_gi, bcols_gi, bvals_gi, tmp, gt3, G_N);
    mean4<<<cdiv(G_N * 32, 256), 256, 0, stream>>>(gemb0, gt1, gi2, gt3, gemb, G_N * 32);

    // --- social user: acc = ue0 + Ov@ue0 + Ov@(Ov@ue0) ---
    copy_f<<<cdiv(U_N * 32, 256), 256, 0, stream>>>(accu, uefu, U_N * 32);
    dense_nx32<<<cdiv(U_N, 32), 256, 0, stream>>>(ov_u, uefu, uea, accu, U_N);
    dense_nx32<<<cdiv(U_N, 32), 256, 0, stream>>>(ov_u, uea, ueb, accu, U_N);

    // --- pooling + gate + final mix ---
    pool_members<<<cdiv(G_N * 32, 256), 256, 0, stream>>>(agu, agm, accu, gul);
    gate_kernel<<<cdiv(2 * G_N, 8), 256, 0, stream>>>(gemb, gul, gw1, gb1, gw2, gb2, wg);
    final_mix<<<cdiv(G_N * 32, 256), 256, 0, stream>>>(wg, gemb, gul, gfin);

    // --- item overlap propagation ---
    copy_f<<<cdiv(I_N * 32, 256), 256, 0, stream>>>(iacc, iemb, I_N * 32);
    dense_nx32<<<cdiv(I_N, 32), 256, 0, stream>>>(ov_i, iemb, ita, iacc, I_N);
    dense_nx32<<<cdiv(I_N, 32), 256, 0, stream>>>(ov_i, ita, itb, iacc, I_N);

    // --- predict ---
    predict_kernel<<<cdiv(B_N, 256), 256, 0, stream>>>(gin, iin, gfin, iacc,
                                                       pw1, pb1, pw2, pb2, out);
}

// Round 2
// 1175.194 us; speedup vs baseline: 2.8583x; 2.8583x over previous
//
#include <hip/hip_runtime.h>
#include <math.h>

#define U_N 10000
#define G_N 3000
#define I_N 8000
#define D_N 32
#define NNZ_UI 720000
#define NNZ_GI 440000
#define L_MEM 20
#define B_N 4096
#define UI_N (U_N + I_N)   // 18000
#define GI_N (G_N + I_N)   // 11000
#define CAP 128            // max degree per row (Poisson(40); P(>128) ~ 1e-26)
#define KSPLIT 8           // split-K factor for dense MFMA kernels

static __host__ int cdiv(int a, int b) { return (a + b - 1) / b; }

typedef __attribute__((ext_vector_type(8))) short bf16x8;
typedef __attribute__((ext_vector_type(4))) float f32x4;

__device__ __forceinline__ short f32_to_bf16(float f) {
    unsigned u = __float_as_uint(f);
    unsigned r = (u + 0x7FFFu + ((u >> 16) & 1u)) >> 16;   // RTNE
    return (short)r;
}

// ---------------- utility kernels ----------------

__global__ __launch_bounds__(256) void copy_f(float* __restrict__ dst,
                                              const float* __restrict__ src, int n) {
    int i = blockIdx.x * 256 + threadIdx.x;
    if (i < n) dst[i] = src[i];
}

__global__ __launch_bounds__(256) void add_into(float* __restrict__ dst,
                                                const float* __restrict__ src, int n) {
    int i = blockIdx.x * 256 + threadIdx.x;
    if (i < n) dst[i] += src[i];
}

__global__ __launch_bounds__(256) void mean4(const float* __restrict__ a,
                                             const float* __restrict__ b,
                                             const float* __restrict__ c,
                                             const float* __restrict__ d,
                                             float* __restrict__ out, int n) {
    int i = blockIdx.x * 256 + threadIdx.x;
    if (i < n) out[i] = 0.25f * (a[i] + b[i] + c[i] + d[i]);
}

// ---------------- sparse: bucket build + gather SPMM ----------------

__global__ __launch_bounds__(256) void bucket_fill(const int* __restrict__ rows,
                                                   const int* __restrict__ cols,
                                                   const float* __restrict__ vals,
                                                   int nnz, int* __restrict__ cnt,
                                                   int* __restrict__ bcols,
                                                   float* __restrict__ bvals) {
    int i = blockIdx.x * 256 + threadIdx.x;
    if (i >= nnz) return;
    int r = rows[i];
    int pos = atomicAdd(&cnt[r], 1);
    if (pos < CAP) {
        bcols[(size_t)r * CAP + pos] = cols[i];
        bvals[(size_t)r * CAP + pos] = vals[i];
    }
}

__global__ __launch_bounds__(256) void spmm_bucket(const int* __restrict__ cnt,
                                                   const int* __restrict__ bcols,
                                                   const float* __restrict__ bvals,
                                                   const float* __restrict__ x,
                                                   float* __restrict__ out, int nrows) {
    int row = blockIdx.x * 8 + (threadIdx.x >> 5);
    if (row >= nrows) return;
    int d = threadIdx.x & 31;
    int deg = cnt[row];
    if (deg > CAP) deg = CAP;
    const int* bc = bcols + (size_t)row * CAP;
    const float* bv = bvals + (size_t)row * CAP;
    float acc = 0.f;
    int j = 0;
    for (; j + 1 < deg; j += 2) {
        int c0 = bc[j], c1 = bc[j + 1];
        float v0 = bv[j], v1 = bv[j + 1];
        acc += v0 * x[c0 * 32 + d];
        acc += v1 * x[c1 * 32 + d];
    }
    if (j < deg) acc += bv[j] * x[bc[j] * 32 + d];
    out[(size_t)row * 32 + d] = acc;
}

// ---------------- dense via MFMA: out[N,32] += Ov[N,N] @ x[N,32] ----------------

// Pack x[N,32] fp32 into bf16 B-fragment layout for mfma_f32_16x16x32_bf16.
// Index: ((t*2 + h)*64 + lane)*8 + j  holds  X[c = t*32 + (lane>>4)*8 + j][d = h*16 + (lane&15)]
__global__ __launch_bounds__(256) void pack_xb(const float* __restrict__ x,
                                               short* __restrict__ XB, int N, int ktiles) {
    int idx = blockIdx.x * 256 + threadIdx.x;
    int total = ktiles * 2 * 64;
    if (idx >= total) return;
    int lane = idx & 63;
    int th = idx >> 6;
    int h = th & 1;
    int t = th >> 1;
    int q = lane >> 4;
    int n = (lane & 15) + h * 16;
    short v[8];
#pragma unroll
    for (int j = 0; j < 8; ++j) {
        int c = t * 32 + q * 8 + j;
        v[j] = (c < N) ? f32_to_bf16(x[(size_t)c * 32 + n]) : (short)0;
    }
    short* dst = XB + (size_t)idx * 8;
#pragma unroll
    for (int j = 0; j < 8; ++j) dst[j] = v[j];
}

// Each wave: 16-row strip x one k-chunk (interleaved tiles, stride KSPLIT).
// A converted fp32->bf16 in registers. Partials atomicAdd'ed into out (pre-zeroed).
__global__ __launch_bounds__(256) void dense_mfma(const float* __restrict__ A,
                                                  const short* __restrict__ XB,
                                                  float* __restrict__ out,
                                                  int N, int ktiles) {
    int wid = (blockIdx.x * 256 + threadIdx.x) >> 6;
    int lane = threadIdx.x & 63;
    int strips = N >> 4;
    int strip = wid / KSPLIT;
    int ks = wid - strip * KSPLIT;
    if (strip >= strips) return;
    int r0 = strip << 4;
    int m = lane & 15;
    int q = lane >> 4;
    const float* arow = A + (size_t)(r0 + m) * N + q * 8;   // + c0 + j addresses col c0+q*8+j
    const bf16x8* xb = (const bf16x8*)XB;
    f32x4 acc0 = {0.f, 0.f, 0.f, 0.f};
    f32x4 acc1 = {0.f, 0.f, 0.f, 0.f};
    for (int t = ks; t < ktiles; t += KSPLIT) {
        int c0 = t * 32;
        bf16x8 afrag;
        if (c0 + 32 <= N) {
            float4 lo = *(const float4*)(arow + c0);
            float4 hi = *(const float4*)(arow + c0 + 4);
            afrag[0] = f32_to_bf16(lo.x); afrag[1] = f32_to_bf16(lo.y);
            afrag[2] = f32_to_bf16(lo.z); afrag[3] = f32_to_bf16(lo.w);
            afrag[4] = f32_to_bf16(hi.x); afrag[5] = f32_to_bf16(hi.y);
            afrag[6] = f32_to_bf16(hi.z); afrag[7] = f32_to_bf16(hi.w);
        } else {                                             // tail k-tile (U: c0=9984)
#pragma unroll
            for (int j = 0; j < 8; ++j) {
                int c = c0 + q * 8 + j;
                afrag[j] = (c < N) ? f32_to_bf16(arow[c0 + j]) : (short)0;
            }
        }
        bf16x8 b0 = xb[(size_t)(t * 2 + 0) * 64 + lane];
        bf16x8 b1 = xb[(size_t)(t * 2 + 1) * 64 + lane];
        acc0 = __builtin_amdgcn_mfma_f32_16x16x32_bf16(afrag, b0, acc0, 0, 0, 0);
        acc1 = __builtin_amdgcn_mfma_f32_16x16x32_bf16(afrag, b1, acc1, 0, 0, 0);
    }
    // C/D layout: col = lane&15, row = (lane>>4)*4 + i   [m89-verified]
#pragma unroll
    for (int i = 0; i < 4; ++i) {
        int row = r0 + q * 4 + i;
        atomicAdd(&out[(size_t)row * 32 + m], acc0[i]);
        atomicAdd(&out[(size_t)row * 32 + m + 16], acc1[i]);
    }
}

// ---------------- pooling, gate, final mix, predict ----------------

__global__ __launch_bounds__(256) void pool_members(const int* __restrict__ users,
                                                    const float* __restrict__ mask,
                                                    const float* __restrict__ accu,
                                                    float* __restrict__ gul) {
    int gid = blockIdx.x * 256 + threadIdx.x;
    if (gid >= G_N * 32) return;
    int g = gid >> 5, d = gid & 31;
    float s = 0.f;
#pragma unroll
    for (int l = 0; l < L_MEM; ++l) {
        int u = users[g * L_MEM + l];
        s += mask[g * L_MEM + l] * accu[(size_t)u * 32 + d];
    }
    gul[gid] = s;
}

__global__ __launch_bounds__(256) void gate_kernel(const float* __restrict__ gemb,
                                                   const float* __restrict__ gul,
                                                   const float* __restrict__ W1,
                                                   const float* __restrict__ b1,
                                                   const float* __restrict__ w2,
                                                   const float* __restrict__ b2,
                                                   float* __restrict__ wout) {
    int row = blockIdx.x * 8 + (threadIdx.x >> 5);
    int j = threadIdx.x & 31;
    if (row >= 2 * G_N) return;
    const float* xrow = (row < G_N) ? (gemb + (size_t)row * 32)
                                    : (gul + (size_t)(row - G_N) * 32);
    float xv = xrow[j];
    float h = b1[j];
#pragma unroll
    for (int k = 0; k < 32; ++k) {
        float xk = __shfl(xv, k, 32);
        h = fmaf(xk, W1[k * 32 + j], h);
    }
    h = fmaxf(h, 0.f);
    float t = h * w2[j];
#pragma unroll
    for (int off = 16; off >= 1; off >>= 1) t += __shfl_xor(t, off, 32);
    if (j == 0) wout[row] = 1.f / (1.f + expf(-(t + b2[0])));
}

__global__ __launch_bounds__(256) void final_mix(const float* __restrict__ wout,
                                                 const float* __restrict__ gemb,
                                                 const float* __restrict__ gul,
                                                 float* __restrict__ gfin) {
    int i = blockIdx.x * 256 + threadIdx.x;
    if (i >= G_N * 32) return;
    int g = i >> 5;
    gfin[i] = wout[g] * gemb[i] + wout[G_N + g] * gul[i];
}

__global__ __launch_bounds__(256) void predict_kernel(const int* __restrict__ gidx,
                                                      const int* __restrict__ iidx,
                                                      const float* __restrict__ gfin,
                                                      const float* __restrict__ iacc,
                                                      const float* __restrict__ pw1,
                                                      const float* __restrict__ pb1,
                                                      const float* __restrict__ pw2,
                                                      const float* __restrict__ pb2,
                                                      float* __restrict__ out) {
    int b = blockIdx.x * 256 + threadIdx.x;
    if (b >= B_N) return;
    const float* ge = gfin + (size_t)gidx[b] * 32;
    const float* ie = iacc + (size_t)iidx[b] * 32;
    float p[8];
#pragma unroll
    for (int j = 0; j < 8; ++j) p[j] = pb1[j];
    for (int d = 0; d < 32; ++d) {
        float t = ge[d] * ie[d];
#pragma unroll
        for (int j = 0; j < 8; ++j) p[j] = fmaf(t, pw1[d * 8 + j], p[j]);
    }
    float s = pb2[0];
#pragma unroll
    for (int j = 0; j < 8; ++j) s = fmaf(fmaxf(p[j], 0.f), pw2[j], s);
    out[b] = 1.f / (1.f + expf(-s));
}

// ---------------- launcher ----------------

extern "C" void kernel_launch(void* const* d_in, const int* in_sizes, int n_in,
                              void* d_out, int out_size, void* d_ws, size_t ws_size,
                              hipStream_t stream) {
    const int*   gin   = (const int*)d_in[0];
    const int*   iin   = (const int*)d_in[1];
    const float* uemb  = (const float*)d_in[2];
    const float* gemb0 = (const float*)d_in[3];
    const float* iemb0 = (const float*)d_in[4];
    const int*   uir   = (const int*)d_in[5];
    const int*   uic   = (const int*)d_in[6];
    const float* uiv   = (const float*)d_in[7];
    const int*   gir   = (const int*)d_in[8];
    const int*   gic   = (const int*)d_in[9];
    const float* giv   = (const float*)d_in[10];
    const float* ov_u  = (const float*)d_in[11];
    const float* ov_i  = (const float*)d_in[12];
    const int*   agu   = (const int*)d_in[13];
    const float* agm   = (const float*)d_in[14];
    const float* gw1   = (const float*)d_in[15];
    const float* gb1   = (const float*)d_in[16];
    const float* gw2   = (const float*)d_in[17];
    const float* gb2   = (const float*)d_in[18];
    const float* pw1   = (const float*)d_in[19];
    const float* pb1   = (const float*)d_in[20];
    const float* pw2   = (const float*)d_in[21];
    const float* pb2   = (const float*)d_in[22];
    float* out = (float*)d_out;

    const int KT_U = (U_N + 31) / 32;   // 313 (tail tile of 16)
    const int KT_I = I_N / 32;          // 250

    // bump allocator over d_ws
    char* wp = (char*)d_ws;
    auto alloc = [&](size_t nbytes) -> void* {
        void* p = (void*)wp;
        wp += (nbytes + 255) & ~(size_t)255;
        return p;
    };
    int*   cnt_ui   = (int*)alloc((size_t)UI_N * 4);
    int*   bcols_ui = (int*)alloc((size_t)UI_N * CAP * 4);
    float* bvals_ui = (float*)alloc((size_t)UI_N * CAP * 4);
    int*   cnt_gi   = (int*)alloc((size_t)GI_N * 4);
    int*   bcols_gi = (int*)alloc((size_t)GI_N * CAP * 4);
    float* bvals_gi = (float*)alloc((size_t)GI_N * CAP * 4);

    float* ui0  = (float*)alloc((size_t)UI_N * 32 * 4);
    float* ui1  = (float*)alloc((size_t)UI_N * 32 * 4);
    float* ui2  = (float*)alloc((size_t)UI_N * 32 * 4);
    float* ui3  = (float*)alloc((size_t)UI_N * 32 * 4);
    float* gi0  = (float*)alloc((size_t)GI_N * 32 * 4);
    float* gi1  = (float*)alloc((size_t)GI_N * 32 * 4);
    float* gi2  = (float*)alloc((size_t)GI_N * 32 * 4);
    float* gi3  = (float*)alloc((size_t)GI_N * 32 * 4);
    float* uefu = (float*)alloc((size_t)U_N * 32 * 4);
    float* iefu = (float*)alloc((size_t)I_N * 32 * 4);
    float* iemb = (float*)alloc((size_t)I_N * 32 * 4);
    float* tmp  = (float*)alloc((size_t)GI_N * 32 * 4);
    float* gt1  = (float*)alloc((size_t)G_N * 32 * 4);
    float* gt3  = (float*)alloc((size_t)G_N * 32 * 4);
    float* gemb = (float*)alloc((size_t)G_N * 32 * 4);
    float* accu = (float*)alloc((size_t)U_N * 32 * 4);
    float* uea  = (float*)alloc((size_t)U_N * 32 * 4);
    float* ueb  = (float*)alloc((size_t)U_N * 32 * 4);
    float* gul  = (float*)alloc((size_t)G_N * 32 * 4);
    float* wg   = (float*)alloc((size_t)2 * G_N * 4);
    float* gfin = (float*)alloc((size_t)G_N * 32 * 4);
    float* iacc = (float*)alloc((size_t)I_N * 32 * 4);
    float* ita  = (float*)alloc((size_t)I_N * 32 * 4);
    float* itb  = (float*)alloc((size_t)I_N * 32 * 4);
    short* xbu  = (short*)alloc((size_t)KT_U * 2 * 64 * 8 * 2);
    short* xbi  = (short*)alloc((size_t)KT_I * 2 * 64 * 8 * 2);

    // --- build per-row buckets for both graphs ---
    hipMemsetAsync(cnt_ui, 0, (size_t)UI_N * 4, stream);
    hipMemsetAsync(cnt_gi, 0, (size_t)GI_N * 4, stream);
    bucket_fill<<<cdiv(NNZ_UI, 256), 256, 0, stream>>>(uir, uic, uiv, NNZ_UI,
                                                       cnt_ui, bcols_ui, bvals_ui);
    bucket_fill<<<cdiv(NNZ_GI, 256), 256, 0, stream>>>(gir, gic, giv, NNZ_GI,
                                                       cnt_gi, bcols_gi, bvals_gi);

    // --- user-item propagation (3 layers) ---
    copy_f<<<cdiv(U_N * 32, 256), 256, 0, stream>>>(ui0, uemb, U_N * 32);
    copy_f<<<cdiv(I_N * 32, 256), 256, 0, stream>>>(ui0 + (size_t)U_N * 32, iemb0, I_N * 32);
    spmm_bucket<<<cdiv(UI_N, 8), 256, 0, stream>>>(cnt_ui, bcols_ui, bvals_ui, ui0, ui1, UI_N);
    spmm_bucket<<<cdiv(UI_N, 8), 256, 0, stream>>>(cnt_ui, bcols_ui, bvals_ui, ui1, ui2, UI_N);
    spmm_bucket<<<cdiv(UI_N, 8), 256, 0, stream>>>(cnt_ui, bcols_ui, bvals_ui, ui2, ui3, UI_N);
    mean4<<<cdiv(U_N * 32, 256), 256, 0, stream>>>(ui0, ui1, ui2, ui3, uefu, U_N * 32);
    mean4<<<cdiv(I_N * 32, 256), 256, 0, stream>>>(ui0 + (size_t)U_N * 32, ui1 + (size_t)U_N * 32,
                                                   ui2 + (size_t)U_N * 32, ui3 + (size_t)U_N * 32,
                                                   iefu, I_N * 32);

    // --- group-item propagation (3 layers) ---
    copy_f<<<cdiv(G_N * 32, 256), 256, 0, stream>>>(gi0, gemb0, G_N * 32);
    copy_f<<<cdiv(I_N * 32, 256), 256, 0, stream>>>(gi0 + (size_t)G_N * 32, iefu, I_N * 32);
    spmm_bucket<<<cdiv(GI_N, 8), 256, 0, stream>>>(cnt_gi, bcols_gi, bvals_gi, gi0, gi1, GI_N);
    spmm_bucket<<<cdiv(GI_N, 8), 256, 0, stream>>>(cnt_gi, bcols_gi, bvals_gi, gi1, gi2, GI_N);
    spmm_bucket<<<cdiv(GI_N, 8), 256, 0, stream>>>(cnt_gi, bcols_gi, bvals_gi, gi2, gi3, GI_N);
    mean4<<<cdiv(I_N * 32, 256), 256, 0, stream>>>(gi0 + (size_t)G_N * 32, gi1 + (size_t)G_N * 32,
                                                   gi2 + (size_t)G_N * 32, gi3 + (size_t)G_N * 32,
                                                   iemb, I_N * 32);

    // --- g_layers odd terms ---
    copy_f<<<cdiv(G_N * 32, 256), 256, 0, stream>>>(tmp, gemb0, G_N * 32);
    copy_f<<<cdiv(I_N * 32, 256), 256, 0, stream>>>(tmp + (size_t)G_N * 32, iemb0, I_N * 32);
    spmm_bucket<<<cdiv(G_N, 8), 256, 0, stream>>>(cnt_gi, bcols_gi, bvals_gi, tmp, gt1, G_N);
    copy_f<<<cdiv(I_N * 32, 256), 256, 0, stream>>>(tmp + (size_t)G_N * 32,
                                                    ui2 + (size_t)U_N * 32, I_N * 32);
    spmm_bucket<<<cdiv(G_N, 8), 256, 0, stream>>>(cnt_gi, bcols_gi, bvals_gi, tmp, gt3, G_N);
    mean4<<<cdiv(G_N * 32, 256), 256, 0, stream>>>(gemb0, gt1, gi2, gt3, gemb, G_N * 32);

    // --- social user: acc = ue0 + Ov@ue0 + Ov@(Ov@ue0) via MFMA ---
    const int U_STRIPS = U_N / 16, I_STRIPS = I_N / 16;
    copy_f<<<cdiv(U_N * 32, 256), 256, 0, stream>>>(accu, uefu, U_N * 32);
    pack_xb<<<cdiv(KT_U * 128, 256), 256, 0, stream>>>(uefu, xbu, U_N, KT_U);
    hipMemsetAsync(uea, 0, (size_t)U_N * 32 * 4, stream);
    dense_mfma<<<cdiv(U_STRIPS * KSPLIT, 4), 256, 0, stream>>>(ov_u, xbu, uea, U_N, KT_U);
    add_into<<<cdiv(U_N * 32, 256), 256, 0, stream>>>(accu, uea, U_N * 32);
    pack_xb<<<cdiv(KT_U * 128, 256), 256, 0, stream>>>(uea, xbu, U_N, KT_U);
    hipMemsetAsync(ueb, 0, (size_t)U_N * 32 * 4, stream);
    dense_mfma<<<cdiv(U_STRIPS * KSPLIT, 4), 256, 0, stream>>>(ov_u, xbu, ueb, U_N, KT_U);
    add_into<<<cdiv(U_N * 32, 256), 256, 0, stream>>>(accu, ueb, U_N * 32);

    // --- pooling + gate + final mix ---
    pool_members<<<cdiv(G_N * 32, 256), 256, 0, stream>>>(agu, agm, accu, gul);
    gate_kernel<<<cdiv(2 * G_N, 8), 256, 0, stream>>>(gemb, gul, gw1, gb1, gw2, gb2, wg);
    final_mix<<<cdiv(G_N * 32, 256), 256, 0, stream>>>(wg, gemb, gul, gfin);

    // --- item overlap propagation via MFMA ---
    copy_f<<<cdiv(I_N * 32, 256), 256, 0, stream>>>(iacc, iemb, I_N * 32);
    pack_xb<<<cdiv(KT_I * 128, 256), 256, 0, stream>>>(iemb, xbi, I_N, KT_I);
    hipMemsetAsync(ita, 0, (size_t)I_N * 32 * 4, stream);
    dense_mfma<<<cdiv(I_STRIPS * KSPLIT, 4), 256, 0, stream>>>(ov_i, xbi, ita, I_N, KT_I);
    add_into<<<cdiv(I_N * 32, 256), 256, 0, stream>>>(iacc, ita, I_N * 32);
    pack_xb<<<cdiv(KT_I * 128, 256), 256, 0, stream>>>(ita, xbi, I_N, KT_I);
    hipMemsetAsync(itb, 0, (size_t)I_N * 32 * 4, stream);
    dense_mfma<<<cdiv(I_STRIPS * KSPLIT, 4), 256, 0, stream>>>(ov_i, xbi, itb, I_N, KT_I);
    add_into<<<cdiv(I_N * 32, 256), 256, 0, stream>>>(iacc, itb, I_N * 32);

    // --- predict ---
    predict_kernel<<<cdiv(B_N, 256), 256, 0, stream>>>(gin, iin, gfin, iacc,
                                                       pw1, pb1, pw2, pb2, out);
}

// Round 3
// 1086.897 us; speedup vs baseline: 3.0905x; 1.0812x over previous
//
#include <hip/hip_runtime.h>
#include <math.h>

#define U_N 10000
#define G_N 3000
#define I_N 8000
#define D_N 32
#define NNZ_UI 720000
#define NNZ_GI 440000
#define L_MEM 20
#define B_N 4096
#define UI_N (U_N + I_N)   // 18000
#define GI_N (G_N + I_N)   // 11000
#define CAP 128            // max degree (Poisson(40); P(>128) ~ 1e-26)
#define KSPLIT 8

static __host__ int cdiv(int a, int b) { return (a + b - 1) / b; }

typedef __attribute__((ext_vector_type(8))) short bf16x8;
typedef __attribute__((ext_vector_type(4))) float f32x4;

__device__ __forceinline__ short f32_to_bf16(float f) {
    unsigned u = __float_as_uint(f);
    unsigned r = (u + 0x7FFFu + ((u >> 16) & 1u)) >> 16;   // RTNE
    return (short)r;
}

// ---------------- sparse: bucket build + split-source gather SPMM ----------------

// bucket record: int2 {col, float-bits(val)} -> one 8B store / 8B load per nnz
__global__ __launch_bounds__(256) void bucket_fill(const int* __restrict__ rows,
                                                   const int* __restrict__ cols,
                                                   const float* __restrict__ vals,
                                                   int nnz, int* __restrict__ cnt,
                                                   int2* __restrict__ bkt) {
    int i = blockIdx.x * 256 + threadIdx.x;
    if (i >= nnz) return;
    int r = rows[i];
    int pos = atomicAdd(&cnt[r], 1);
    if (pos < CAP) {
        int2 e; e.x = cols[i]; e.y = __float_as_int(vals[i]);
        bkt[(size_t)r * CAP + pos] = e;
    }
}

// out[row,d] = sum_j val_j * X[col_j, d], X = concat(x1[0:split], x2[...]) logically.
// For contiguous x pass x2 = x1 + split*32.
__global__ __launch_bounds__(256) void spmm_split(const int* __restrict__ cnt,
                                                  const int2* __restrict__ bkt,
                                                  const float* __restrict__ x1,
                                                  const float* __restrict__ x2,
                                                  int split,
                                                  float* __restrict__ out, int nrows) {
    int row = blockIdx.x * 8 + (threadIdx.x >> 5);
    if (row >= nrows) return;
    int d = threadIdx.x & 31;
    int deg = cnt[row];
    if (deg > CAP) deg = CAP;
    const int2* bk = bkt + (size_t)row * CAP;
    float acc = 0.f;
    int j = 0;
#define GATHER(e) ((e.x < split) ? x1[(size_t)e.x * 32 + d] \
                                 : x2[(size_t)(e.x - split) * 32 + d])
    for (; j + 3 < deg; j += 4) {
        int2 e0 = bk[j], e1 = bk[j + 1], e2 = bk[j + 2], e3 = bk[j + 3];
        float g0 = GATHER(e0), g1 = GATHER(e1), g2 = GATHER(e2), g3 = GATHER(e3);
        acc = fmaf(__int_as_float(e0.y), g0, acc);
        acc = fmaf(__int_as_float(e1.y), g1, acc);
        acc = fmaf(__int_as_float(e2.y), g2, acc);
        acc = fmaf(__int_as_float(e3.y), g3, acc);
    }
    for (; j < deg; ++j) {
        int2 e = bk[j];
        acc = fmaf(__int_as_float(e.y), GATHER(e), acc);
    }
#undef GATHER
    out[(size_t)row * 32 + d] = acc;
}

// ---------------- fused means ----------------

// user rows: uefu = accu = mean(uemb, ui1..3); item rows: iefu = mean(iemb0, ui1..3)
__global__ __launch_bounds__(256) void mean_ui(const float* __restrict__ uemb,
                                               const float* __restrict__ iemb0,
                                               const float* __restrict__ ui1,
                                               const float* __restrict__ ui2,
                                               const float* __restrict__ ui3,
                                               float* __restrict__ uefu,
                                               float* __restrict__ accu,
                                               float* __restrict__ iefu) {
    int idx = blockIdx.x * 256 + threadIdx.x;
    if (idx >= UI_N * 32) return;
    const int UOFF = U_N * 32;
    float base = (idx < UOFF) ? uemb[idx] : iemb0[idx - UOFF];
    float m = 0.25f * (base + ui1[idx] + ui2[idx] + ui3[idx]);
    if (idx < UOFF) { uefu[idx] = m; accu[idx] = m; }
    else iefu[idx - UOFF] = m;
}

// items of gi: iemb = iacc = mean(iefu, gi1..3 item parts)
__global__ __launch_bounds__(256) void mean_gi_items(const float* __restrict__ iefu,
                                                     const float* __restrict__ gi1,
                                                     const float* __restrict__ gi2,
                                                     const float* __restrict__ gi3,
                                                     float* __restrict__ iemb,
                                                     float* __restrict__ iacc) {
    int idx = blockIdx.x * 256 + threadIdx.x;
    if (idx >= I_N * 32) return;
    const int GOFF = G_N * 32;
    float m = 0.25f * (iefu[idx] + gi1[GOFF + idx] + gi2[GOFF + idx] + gi3[GOFF + idx]);
    iemb[idx] = m;
    iacc[idx] = m;
}

__global__ __launch_bounds__(256) void mean_g(const float* __restrict__ gemb0,
                                              const float* __restrict__ gt1,
                                              const float* __restrict__ gi2,
                                              const float* __restrict__ gt3,
                                              float* __restrict__ gemb) {
    int idx = blockIdx.x * 256 + threadIdx.x;
    if (idx >= G_N * 32) return;
    gemb[idx] = 0.25f * (gemb0[idx] + gt1[idx] + gi2[idx] + gt3[idx]);
}

// ---------------- dense via MFMA: out += Ov @ x (and optionally out2 += too) ----------------

// Pack x[N,32] fp32 -> bf16 B-fragment layout for mfma_f32_16x16x32_bf16.
__global__ __launch_bounds__(256) void pack_xb(const float* __restrict__ x,
                                               short* __restrict__ XB, int N, int ktiles) {
    int idx = blockIdx.x * 256 + threadIdx.x;
    int total = ktiles * 2 * 64;
    if (idx >= total) return;
    int lane = idx & 63;
    int th = idx >> 6;
    int h = th & 1;
    int t = th >> 1;
    int q = lane >> 4;
    int n = (lane & 15) + h * 16;
    short v[8];
#pragma unroll
    for (int j = 0; j < 8; ++j) {
        int c = t * 32 + q * 8 + j;
        v[j] = (c < N) ? f32_to_bf16(x[(size_t)c * 32 + n]) : (short)0;
    }
    short* dst = XB + (size_t)idx * 8;
#pragma unroll
    for (int j = 0; j < 8; ++j) dst[j] = v[j];
}

__global__ __launch_bounds__(256) void dense_mfma(const float* __restrict__ A,
                                                  const short* __restrict__ XB,
                                                  float* __restrict__ out,
                                                  float* __restrict__ out2,
                                                  int N, int ktiles) {
    int wid = (blockIdx.x * 256 + threadIdx.x) >> 6;
    int lane = threadIdx.x & 63;
    int strips = N >> 4;
    int strip = wid / KSPLIT;
    int ks = wid - strip * KSPLIT;
    if (strip >= strips) return;
    int r0 = strip << 4;
    int m = lane & 15;
    int q = lane >> 4;
    const float* arow = A + (size_t)(r0 + m) * N + q * 8;
    const bf16x8* xb = (const bf16x8*)XB;
    f32x4 acc0 = {0.f, 0.f, 0.f, 0.f};
    f32x4 acc1 = {0.f, 0.f, 0.f, 0.f};
    for (int t = ks; t < ktiles; t += KSPLIT) {
        int c0 = t * 32;
        bf16x8 afrag;
        if (c0 + 32 <= N) {
            float4 lo = *(const float4*)(arow + c0);
            float4 hi = *(const float4*)(arow + c0 + 4);
            afrag[0] = f32_to_bf16(lo.x); afrag[1] = f32_to_bf16(lo.y);
            afrag[2] = f32_to_bf16(lo.z); afrag[3] = f32_to_bf16(lo.w);
            afrag[4] = f32_to_bf16(hi.x); afrag[5] = f32_to_bf16(hi.y);
            afrag[6] = f32_to_bf16(hi.z); afrag[7] = f32_to_bf16(hi.w);
        } else {                                             // tail k-tile (U: c0=9984)
#pragma unroll
            for (int j = 0; j < 8; ++j) {
                int c = c0 + q * 8 + j;
                afrag[j] = (c < N) ? f32_to_bf16(arow[c0 + j]) : (short)0;
            }
        }
        bf16x8 b0 = xb[(size_t)(t * 2 + 0) * 64 + lane];
        bf16x8 b1 = xb[(size_t)(t * 2 + 1) * 64 + lane];
        acc0 = __builtin_amdgcn_mfma_f32_16x16x32_bf16(afrag, b0, acc0, 0, 0, 0);
        acc1 = __builtin_amdgcn_mfma_f32_16x16x32_bf16(afrag, b1, acc1, 0, 0, 0);
    }
    // C/D layout: col = lane&15, row = (lane>>4)*4 + i
#pragma unroll
    for (int i = 0; i < 4; ++i) {
        size_t o = (size_t)(r0 + q * 4 + i) * 32 + m;
        atomicAdd(&out[o], acc0[i]);
        atomicAdd(&out[o + 16], acc1[i]);
        if (out2) {
            atomicAdd(&out2[o], acc0[i]);
            atomicAdd(&out2[o + 16], acc1[i]);
        }
    }
}

// ---------------- fused pool + gate + final mix ----------------
// one 32-lane group per group g
__global__ __launch_bounds__(256) void pool_gate_mix(const int* __restrict__ users,
                                                     const float* __restrict__ mask,
                                                     const float* __restrict__ accu,
                                                     const float* __restrict__ gemb,
                                                     const float* __restrict__ W1,
                                                     const float* __restrict__ b1,
                                                     const float* __restrict__ w2,
                                                     const float* __restrict__ b2,
                                                     float* __restrict__ gfin) {
    int g = blockIdx.x * 8 + (threadIdx.x >> 5);
    if (g >= G_N) return;
    int j = threadIdx.x & 31;
    // pool
    float gl = 0.f;
#pragma unroll
    for (int l = 0; l < L_MEM; ++l) {
        int u = users[g * L_MEM + l];
        gl = fmaf(mask[g * L_MEM + l], accu[(size_t)u * 32 + j], gl);
    }
    float ge = gemb[(size_t)g * 32 + j];
    // gate(ge) and gate(gl)
    float h1 = b1[j], h2 = b1[j];
#pragma unroll
    for (int k = 0; k < 32; ++k) {
        float w = W1[k * 32 + j];
        h1 = fmaf(__shfl(ge, k, 32), w, h1);
        h2 = fmaf(__shfl(gl, k, 32), w, h2);
    }
    float w2j = w2[j];
    float t1 = fmaxf(h1, 0.f) * w2j;
    float t2 = fmaxf(h2, 0.f) * w2j;
#pragma unroll
    for (int off = 16; off >= 1; off >>= 1) {
        t1 += __shfl_xor(t1, off, 32);
        t2 += __shfl_xor(t2, off, 32);
    }
    float bb = b2[0];
    float wa = 1.f / (1.f + expf(-(t1 + bb)));
    float wb = 1.f / (1.f + expf(-(t2 + bb)));
    gfin[(size_t)g * 32 + j] = wa * ge + wb * gl;
}

__global__ __launch_bounds__(256) void predict_kernel(const int* __restrict__ gidx,
                                                      const int* __restrict__ iidx,
                                                      const float* __restrict__ gfin,
                                                      const float* __restrict__ iacc,
                                                      const float* __restrict__ pw1,
                                                      const float* __restrict__ pb1,
                                                      const float* __restrict__ pw2,
                                                      const float* __restrict__ pb2,
                                                      float* __restrict__ out) {
    int b = blockIdx.x * 256 + threadIdx.x;
    if (b >= B_N) return;
    const float* ge = gfin + (size_t)gidx[b] * 32;
    const float* ie = iacc + (size_t)iidx[b] * 32;
    float p[8];
#pragma unroll
    for (int j = 0; j < 8; ++j) p[j] = pb1[j];
    for (int d = 0; d < 32; ++d) {
        float t = ge[d] * ie[d];
#pragma unroll
        for (int j = 0; j < 8; ++j) p[j] = fmaf(t, pw1[d * 8 + j], p[j]);
    }
    float s = pb2[0];
#pragma unroll
    for (int j = 0; j < 8; ++j) s = fmaf(fmaxf(p[j], 0.f), pw2[j], s);
    out[b] = 1.f / (1.f + expf(-s));
}

// ---------------- launcher ----------------

extern "C" void kernel_launch(void* const* d_in, const int* in_sizes, int n_in,
                              void* d_out, int out_size, void* d_ws, size_t ws_size,
                              hipStream_t stream) {
    const int*   gin   = (const int*)d_in[0];
    const int*   iin   = (const int*)d_in[1];
    const float* uemb  = (const float*)d_in[2];
    const float* gemb0 = (const float*)d_in[3];
    const float* iemb0 = (const float*)d_in[4];
    const int*   uir   = (const int*)d_in[5];
    const int*   uic   = (const int*)d_in[6];
    const float* uiv   = (const float*)d_in[7];
    const int*   gir   = (const int*)d_in[8];
    const int*   gic   = (const int*)d_in[9];
    const float* giv   = (const float*)d_in[10];
    const float* ov_u  = (const float*)d_in[11];
    const float* ov_i  = (const float*)d_in[12];
    const int*   agu   = (const int*)d_in[13];
    const float* agm   = (const float*)d_in[14];
    const float* gw1   = (const float*)d_in[15];
    const float* gb1   = (const float*)d_in[16];
    const float* gw2   = (const float*)d_in[17];
    const float* gb2   = (const float*)d_in[18];
    const float* pw1   = (const float*)d_in[19];
    const float* pb1   = (const float*)d_in[20];
    const float* pw2   = (const float*)d_in[21];
    const float* pb2   = (const float*)d_in[22];
    float* out = (float*)d_out;

    const int KT_U = (U_N + 31) / 32;   // 313
    const int KT_I = I_N / 32;          // 250

    char* wp = (char*)d_ws;
    auto alloc = [&](size_t nbytes) -> void* {
        void* p = (void*)wp;
        wp += (nbytes + 255) & ~(size_t)255;
        return p;
    };
    // counters adjacent -> one memset
    int*   cnt_ui = (int*)alloc((size_t)UI_N * 4);
    int*   cnt_gi = (int*)alloc((size_t)GI_N * 4);
    int2*  bkt_ui = (int2*)alloc((size_t)UI_N * CAP * 8);
    int2*  bkt_gi = (int2*)alloc((size_t)GI_N * CAP * 8);
    // dense split-K partial targets adjacent -> one memset
    float* uea  = (float*)alloc((size_t)U_N * 32 * 4);
    float* ita  = (float*)alloc((size_t)I_N * 32 * 4);

    float* ui1  = (float*)alloc((size_t)UI_N * 32 * 4);
    float* ui2  = (float*)alloc((size_t)UI_N * 32 * 4);
    float* ui3  = (float*)alloc((size_t)UI_N * 32 * 4);
    float* gi1  = (float*)alloc((size_t)GI_N * 32 * 4);
    float* gi2  = (float*)alloc((size_t)GI_N * 32 * 4);
    float* gi3  = (float*)alloc((size_t)GI_N * 32 * 4);
    float* uefu = (float*)alloc((size_t)U_N * 32 * 4);
    float* iefu = (float*)alloc((size_t)I_N * 32 * 4);
    float* iemb = (float*)alloc((size_t)I_N * 32 * 4);
    float* gt1  = (float*)alloc((size_t)G_N * 32 * 4);
    float* gt3  = (float*)alloc((size_t)G_N * 32 * 4);
    float* gemb = (float*)alloc((size_t)G_N * 32 * 4);
    float* accu = (float*)alloc((size_t)U_N * 32 * 4);
    float* gfin = (float*)alloc((size_t)G_N * 32 * 4);
    float* iacc = (float*)alloc((size_t)I_N * 32 * 4);
    short* xbu  = (short*)alloc((size_t)KT_U * 2 * 64 * 8 * 2);
    short* xbi  = (short*)alloc((size_t)KT_I * 2 * 64 * 8 * 2);

    // --- buckets ---
    hipMemsetAsync(cnt_ui, 0, (size_t)(UI_N + GI_N) * 4 + 256, stream); // covers both (adjacent allocs)
    bucket_fill<<<cdiv(NNZ_UI, 256), 256, 0, stream>>>(uir, uic, uiv, NNZ_UI, cnt_ui, bkt_ui);
    bucket_fill<<<cdiv(NNZ_GI, 256), 256, 0, stream>>>(gir, gic, giv, NNZ_GI, cnt_gi, bkt_gi);
    hipMemsetAsync(uea, 0, (size_t)(U_N + I_N) * 32 * 4 + 256, stream); // uea + ita

    // --- user-item propagation (3 layers; layer1 reads split sources) ---
    spmm_split<<<cdiv(UI_N, 8), 256, 0, stream>>>(cnt_ui, bkt_ui, uemb, iemb0, U_N, ui1, UI_N);
    spmm_split<<<cdiv(UI_N, 8), 256, 0, stream>>>(cnt_ui, bkt_ui, ui1, ui1 + (size_t)U_N * 32, U_N, ui2, UI_N);
    spmm_split<<<cdiv(UI_N, 8), 256, 0, stream>>>(cnt_ui, bkt_ui, ui2, ui2 + (size_t)U_N * 32, U_N, ui3, UI_N);
    mean_ui<<<cdiv(UI_N * 32, 256), 256, 0, stream>>>(uemb, iemb0, ui1, ui2, ui3, uefu, accu, iefu);

    // --- group-item propagation ---
    spmm_split<<<cdiv(GI_N, 8), 256, 0, stream>>>(cnt_gi, bkt_gi, gemb0, iefu, G_N, gi1, GI_N);
    spmm_split<<<cdiv(GI_N, 8), 256, 0, stream>>>(cnt_gi, bkt_gi, gi1, gi1 + (size_t)G_N * 32, G_N, gi2, GI_N);
    spmm_split<<<cdiv(GI_N, 8), 256, 0, stream>>>(cnt_gi, bkt_gi, gi2, gi2 + (size_t)G_N * 32, G_N, gi3, GI_N);
    mean_gi_items<<<cdiv(I_N * 32, 256), 256, 0, stream>>>(iefu, gi1, gi2, gi3, iemb, iacc);

    // --- g_layers odd terms (rows < G only) ---
    spmm_split<<<cdiv(G_N, 8), 256, 0, stream>>>(cnt_gi, bkt_gi, gemb0, iemb0, G_N, gt1, G_N);
    spmm_split<<<cdiv(G_N, 8), 256, 0, stream>>>(cnt_gi, bkt_gi, gemb0, ui2 + (size_t)U_N * 32, G_N, gt3, G_N);
    mean_g<<<cdiv(G_N * 32, 256), 256, 0, stream>>>(gemb0, gt1, gi2, gt3, gemb);

    // --- social user: accu = uefu + Ov@uefu + Ov@(Ov@uefu) ---
    const int U_STRIPS = U_N / 16, I_STRIPS = I_N / 16;
    pack_xb<<<cdiv(KT_U * 128, 256), 256, 0, stream>>>(uefu, xbu, U_N, KT_U);
    dense_mfma<<<cdiv(U_STRIPS * KSPLIT, 4), 256, 0, stream>>>(ov_u, xbu, uea, accu, U_N, KT_U);
    pack_xb<<<cdiv(KT_U * 128, 256), 256, 0, stream>>>(uea, xbu, U_N, KT_U);
    dense_mfma<<<cdiv(U_STRIPS * KSPLIT, 4), 256, 0, stream>>>(ov_u, xbu, accu, nullptr, U_N, KT_U);

    // --- pool + gate + final mix ---
    pool_gate_mix<<<cdiv(G_N, 8), 256, 0, stream>>>(agu, agm, accu, gemb,
                                                    gw1, gb1, gw2, gb2, gfin);

    // --- item overlap: iacc = iemb + Ov@iemb + Ov@(Ov@iemb) ---
    pack_xb<<<cdiv(KT_I * 128, 256), 256, 0, stream>>>(iemb, xbi, I_N, KT_I);
    dense_mfma<<<cdiv(I_STRIPS * KSPLIT, 4), 256, 0, stream>>>(ov_i, xbi, ita, iacc, I_N, KT_I);
    pack_xb<<<cdiv(KT_I * 128, 256), 256, 0, stream>>>(ita, xbi, I_N, KT_I);
    dense_mfma<<<cdiv(I_STRIPS * KSPLIT, 4), 256, 0, stream>>>(ov_i, xbi, iacc, nullptr, I_N, KT_I);

    // --- predict ---
    predict_kernel<<<cdiv(B_N, 256), 256, 0, stream>>>(gin, iin, gfin, iacc,
                                                       pw1, pb1, pw2, pb2, out);
}